// Round 2
// baseline (209.891 us; speedup 1.0000x reference)
//
#include <hip/hip_runtime.h>
#include <float.h>

#define N_VOX 32768
#define N_CODES 8192
#define DIM 64

// output float offsets (flat, in return order)
#define Q_OFF 0
#define VQ_OFF (N_VOX * DIM)      // 2097152
#define CM_OFF (VQ_OFF + 1)
#define IDX_OFF (VQ_OFF + 2)

// workspace float offsets
#define WS_ACC 0
#define WS_CNT 1                      // int: blocks-done counter
#define WS_ESQH 64                    // 8192 floats: ||e||^2 / 2
#define WS_IDX (WS_ESQH + N_CODES)    // (unused, layout kept)
#define WS_EHI (WS_IDX + N_VOX)       // codebook hi-plane f16 (1 MB, linear)
#define WS_ELO (WS_EHI + N_CODES * DIM / 2)  // lo-plane f16 (1 MB, linear)

typedef _Float16 half8 __attribute__((ext_vector_type(8)));
typedef float floatx4 __attribute__((ext_vector_type(4)));

// ---------------------------------------------------------------- k_cvt
// Pre-convert codebook to hi/lo f16 planes (LINEAR layout now) + esq/2.
__global__ __launch_bounds__(256) void k_cvt(const float* __restrict__ e,
                                             float* __restrict__ ws) {
  int gid = blockIdx.x * 256 + threadIdx.x;
  if (gid == 0) {                            // ws is poisoned each run
    ws[WS_ACC] = 0.f;
    ((int*)ws)[WS_CNT] = 0;
  }
  int row = gid >> 3, c = gid & 7;
  const float* src = e + (size_t)row * DIM + c * 8;
  float4 a = *(const float4*)src;
  float4 b = *(const float4*)(src + 4);
  float x[8] = {a.x, a.y, a.z, a.w, b.x, b.y, b.z, b.w};
  float s = 0.f;
  half8 hv, lv;
  #pragma unroll
  for (int j = 0; j < 8; ++j) {
    s += x[j] * x[j];                        // esq in full fp32 from originals
    _Float16 h = (_Float16)x[j];
    hv[j] = h;
    lv[j] = (_Float16)(x[j] - (float)h);
  }
  s += __shfl_xor(s, 1); s += __shfl_xor(s, 2); s += __shfl_xor(s, 4);
  if (c == 0) ws[WS_ESQH + row] = 0.5f * s;
  ((half8*)(ws + WS_EHI))[row * 8 + c] = hv;
  ((half8*)(ws + WS_ELO))[row * 8 + c] = lv;
}

// ---------------------------------------------------------------- k_argmin
// Block: 64 voxels, 4 waves. Each wave: ALL 64 voxels x a disjoint 2048-code
// quarter (zero duplicate B reads). B fragments loaded DIRECTLY from the
// L2-resident f16 planes into VGPRs (per-lane global_load_dwordx4 == MFMA
// B-fragment layout) -- no LDS staging, no barriers in the main loop.
// Software-pipelined one 32-code tile deep via named register double-buffer.
// Distance surrogate: s = dot - esq/2 (maximize); esq/2 folded into MFMA C-init.
// dot via 3-term f16 split: hh + hl + lh.
__device__ __forceinline__ floatx4 mfma16(half8 a, half8 b, floatx4 c) {
  return __builtin_amdgcn_mfma_f32_16x16x32_f16(a, b, c, 0, 0, 0);
}

__device__ __forceinline__ void comps(const half8 (&ahi)[4][2],
                                      const half8 (&alo)[4][2],
                                      half8 bh0, half8 bh1, half8 bl0, half8 bl1,
                                      float eh, int code,
                                      float (&bmax)[4][4], int (&bidx)[4][4]) {
  #pragma unroll
  for (int m = 0; m < 4; ++m) {
    floatx4 acc = {-eh, -eh, -eh, -eh};
    acc = mfma16(ahi[m][0], bh0, acc);
    acc = mfma16(ahi[m][1], bh1, acc);
    acc = mfma16(ahi[m][0], bl0, acc);
    acc = mfma16(ahi[m][1], bl1, acc);
    acc = mfma16(alo[m][0], bh0, acc);
    acc = mfma16(alo[m][1], bh1, acc);
    // C layout: col = lane&15 (this lane's code), row = quad*4 + r
    #pragma unroll
    for (int r = 0; r < 4; ++r)
      if (acc[r] > bmax[m][r]) { bmax[m][r] = acc[r]; bidx[m][r] = code; }
  }
}

__global__ __launch_bounds__(256, 2) void k_argmin(const float* __restrict__ z,
                                                   const float* __restrict__ e,
                                                   float* __restrict__ ws,
                                                   float* __restrict__ out) {
  __shared__ float sMval[4][64];
  __shared__ int   sMidx[4][64];
  __shared__ int   sWin[64];
  __shared__ float sWsum[4];

  const int tid  = threadIdx.x;
  const int lane = tid & 63;
  const int wave = tid >> 6;       // code-quarter owner
  const int n16  = lane & 15;
  const int quad = lane >> 4;
  const int vb   = blockIdx.x * 64;
  const int wcode = wave * 2048;

  // A fragments: 64 voxels x 64 dims, hi/lo. A[m][kc]: row=n16, k=quad*8+j
  half8 ahi[4][2], alo[4][2];
  #pragma unroll
  for (int m = 0; m < 4; ++m)
    #pragma unroll
    for (int kc = 0; kc < 2; ++kc) {
      const float* src = z + (size_t)(vb + m * 16 + n16) * DIM
                       + kc * 32 + quad * 8;
      float4 a = *(const float4*)src;
      float4 b = *(const float4*)(src + 4);
      float x[8] = {a.x, a.y, a.z, a.w, b.x, b.y, b.z, b.w};
      #pragma unroll
      for (int j = 0; j < 8; ++j) {
        _Float16 h = (_Float16)x[j];
        ahi[m][kc][j] = h;
        alo[m][kc][j] = (_Float16)(x[j] - (float)h);
      }
    }

  float bmax[4][4]; int bidx[4][4];
  #pragma unroll
  for (int m = 0; m < 4; ++m)
    #pragma unroll
    for (int r = 0; r < 4; ++r) { bmax[m][r] = -FLT_MAX; bidx[m][r] = 0; }

  // per-lane fragment base pointers into the linear f16 planes
  const char* pHi = (const char*)(ws + WS_EHI)
                  + (size_t)(wcode + n16) * 128 + quad * 16;
  const char* pLo = (const char*)(ws + WS_ELO)
                  + (size_t)(wcode + n16) * 128 + quad * 16;
  const char* pEs = (const char*)(ws + WS_ESQH) + (size_t)(wcode + n16) * 4;

  // one 32-code tile = two 16-code MFMA column blocks (t0/t1), hi+lo, kc0/kc1
#define LOADT(ct, H00, H01, H10, H11, L00, L01, L10, L11, E0, E1)  \
  {                                                                \
    size_t o = (size_t)(ct) * 4096;                                \
    H00 = *(const half8*)(pHi + o);                                \
    H01 = *(const half8*)(pHi + o + 64);                           \
    H10 = *(const half8*)(pHi + o + 2048);                         \
    H11 = *(const half8*)(pHi + o + 2112);                         \
    L00 = *(const half8*)(pLo + o);                                \
    L01 = *(const half8*)(pLo + o + 64);                           \
    L10 = *(const half8*)(pLo + o + 2048);                         \
    L11 = *(const half8*)(pLo + o + 2112);                         \
    E0 = *(const float*)(pEs + (size_t)(ct) * 128);                \
    E1 = *(const float*)(pEs + (size_t)(ct) * 128 + 64);           \
  }

#define COMPT(ct, H00, H01, H10, H11, L00, L01, L10, L11, E0, E1)            \
  {                                                                          \
    comps(ahi, alo, H00, H01, L00, L01, E0, wcode + (ct) * 32 + n16,         \
          bmax, bidx);                                                       \
    comps(ahi, alo, H10, H11, L10, L11, E1, wcode + (ct) * 32 + 16 + n16,    \
          bmax, bidx);                                                       \
  }

  half8 xh00, xh01, xh10, xh11, xl00, xl01, xl10, xl11; float xe0, xe1;
  half8 yh00, yh01, yh10, yh11, yl00, yl01, yl10, yl11; float ye0, ye1;

  LOADT(0, xh00, xh01, xh10, xh11, xl00, xl01, xl10, xl11, xe0, xe1);
  for (int ct = 0; ct < 64; ct += 2) {
    LOADT(ct + 1, yh00, yh01, yh10, yh11, yl00, yl01, yl10, yl11, ye0, ye1);
    COMPT(ct, xh00, xh01, xh10, xh11, xl00, xl01, xl10, xl11, xe0, xe1);
    if (ct + 2 < 64)
      LOADT(ct + 2, xh00, xh01, xh10, xh11, xl00, xl01, xl10, xl11, xe0, xe1);
    COMPT(ct + 1, yh00, yh01, yh10, yh11, yl00, yl01, yl10, yl11, ye0, ye1);
  }
#undef LOADT
#undef COMPT

  // reduce across the 16 lanes (n16 = code col) holding each voxel's partials
  #pragma unroll
  for (int m = 0; m < 4; ++m)
    #pragma unroll
    for (int r = 0; r < 4; ++r) {
      float v = bmax[m][r]; int i = bidx[m][r];
      #pragma unroll
      for (int off = 1; off < 16; off <<= 1) {
        float ov = __shfl_xor(v, off);
        int   oi = __shfl_xor(i, off);
        if (ov > v || (ov == v && oi < i)) { v = ov; i = oi; }
      }
      if (n16 == 0) {
        int vox = m * 16 + quad * 4 + r;
        sMval[wave][vox] = v;
        sMidx[wave][vox] = i;
      }
    }
  __syncthreads();

  // merge the four code-quarters, publish winner index
  if (tid < 64) {
    float v = sMval[0][tid]; int i = sMidx[0][tid];
    #pragma unroll
    for (int q = 1; q < 4; ++q) {
      float ov = sMval[q][tid]; int oi = sMidx[q][tid];
      if (ov > v || (ov == v && oi < i)) { v = ov; i = oi; }
    }
    sWin[tid] = i;
    out[IDX_OFF + vb + tid] = (float)i;
  }
  __syncthreads();

  // fused k_out: gather quantized rows (exact fp32), accumulate (z-q)^2
  {
    const int vox = tid >> 2;
    const int dc = (tid & 3) * 16;
    const int gi = sWin[vox];
    const float* er = e + (size_t)gi * DIM + dc;
    const float* zr = z + (size_t)(vb + vox) * DIM + dc;
    float* qr = out + Q_OFF + (size_t)(vb + vox) * DIM + dc;
    float local = 0.f;
    #pragma unroll
    for (int j = 0; j < 4; ++j) {
      float4 e4 = *(const float4*)(er + j * 4);
      float4 z4 = *(const float4*)(zr + j * 4);
      *(float4*)(qr + j * 4) = e4;
      float dx = z4.x - e4.x, dy = z4.y - e4.y, dz = z4.z - e4.z, dw = z4.w - e4.w;
      local += dx * dx + dy * dy + dz * dz + dw * dw;
    }
    #pragma unroll
    for (int off = 32; off; off >>= 1) local += __shfl_xor(local, off);
    if ((tid & 63) == 0) sWsum[wave] = local;
    __syncthreads();
    if (tid == 0) {
      float bs = sWsum[0] + sWsum[1] + sWsum[2] + sWsum[3];
      atomicAdd(ws + WS_ACC, bs);            // device-scope
      __threadfence();
      int done = atomicAdd((int*)ws + WS_CNT, 1);
      if (done == (int)gridDim.x - 1) {      // last block: finalize scalars
        float s = atomicAdd(ws + WS_ACC, 0.f);   // atomic read (coherent)
        float mv = s * (1.0f / (float)(N_VOX * DIM));
        out[VQ_OFF] = mv;   // vq_loss
        out[CM_OFF] = mv;   // commitment_loss (identical forward value)
      }
    }
  }
}

// ----------------------------------------------------------------
extern "C" void kernel_launch(void* const* d_in, const int* in_sizes, int n_in,
                              void* d_out, int out_size, void* d_ws, size_t ws_size,
                              hipStream_t stream) {
  const float* z = (const float*)d_in[0];
  const float* e = (const float*)d_in[1];
  float* out = (float*)d_out;
  float* ws = (float*)d_ws;

  k_cvt<<<(N_CODES * 8) / 256, 256, 0, stream>>>(e, ws);
  k_argmin<<<N_VOX / 64, 256, 0, stream>>>(z, e, ws, out);
}